// Round 1
// baseline (256.617 us; speedup 1.0000x reference)
//
#include <hip/hip_runtime.h>
#include <math.h>

// Tile geometry: each block computes a 64x16 output tile for one (batch, tile) pair,
// iterating the 3 input channels sequentially and accumulating gx^2+gy^2.
// 7x7 total stencil (5x5 gaussian then 3x3 sobel) -> halo of 3.
#define TX 64
#define TY 16
#define HALO 3
#define IW (TX + 6)   // 70: img tile width
#define IH (TY + 6)   // 22: img tile height
#define TW (TX + 2)   // 66: tmp/blur width (sobel halo 1)
#define BH (TY + 2)   // 18: blur height
#define IW_P 72       // padded LDS strides
#define TW_P 68

__global__ __launch_bounds__(256)
void edge_fused_kernel(const float* __restrict__ img,
                       const float* __restrict__ gauss,
                       const float* __restrict__ sobel,
                       float* __restrict__ out,
                       unsigned int* __restrict__ gmax,
                       int B, int H, int W) {
    __shared__ float s_img[IH][IW_P];
    __shared__ float s_tmp[IH][TW_P];
    __shared__ float s_blur[BH][TW_P];
    __shared__ float s_red[4];

    const int tid = threadIdx.x;
    const int tiles_x = W / TX;   // 8
    const int tiles_y = H / TY;   // 32
    int bid = blockIdx.x;
    const int tx = bid % tiles_x; bid /= tiles_x;
    const int ty = bid % tiles_y; bid /= tiles_y;
    const int b  = bid;

    const int x0 = tx * TX;
    const int y0 = ty * TY;

    // Filter coefficients (broadcast loads, L1-served)
    const float g0 = gauss[0], g1 = gauss[1], g2 = gauss[2], g3 = gauss[3], g4 = gauss[4];
    float sb[9];
#pragma unroll
    for (int i = 0; i < 9; ++i) sb[i] = sobel[i];

    const int lx  = tid & 63;   // 0..63 -> output column in tile
    const int lyb = tid >> 6;   // 0..3  -> row group; thread owns rows lyb*4 .. lyb*4+3

    float acc[4] = {0.f, 0.f, 0.f, 0.f};

    for (int c = 0; c < 3; ++c) {
        const float* imgc = img + ((size_t)(b * 3 + c) * H) * W;

        // 1. global -> LDS img tile with halo, zero-padded outside image
        for (int idx = tid; idx < IH * IW; idx += 256) {
            const int iy = idx / IW;
            const int ix = idx - iy * IW;
            const int gy_ = y0 - HALO + iy;
            const int gx_ = x0 - HALO + ix;
            float v = 0.f;
            if ((unsigned)gy_ < (unsigned)H && (unsigned)gx_ < (unsigned)W)
                v = imgc[(size_t)gy_ * W + gx_];
            s_img[iy][ix] = v;
        }
        __syncthreads();

        // 2. horizontal 1x5 blur: tmp[y][x], y in [0,IH), x in [0,TW)
        for (int idx = tid; idx < IH * TW; idx += 256) {
            const int yy = idx / TW;
            const int xx = idx - yy * TW;
            s_tmp[yy][xx] = s_img[yy][xx]     * g0 + s_img[yy][xx + 1] * g1
                          + s_img[yy][xx + 2] * g2 + s_img[yy][xx + 3] * g3
                          + s_img[yy][xx + 4] * g4;
        }
        __syncthreads();

        // 3. vertical 5x1 blur; IMPORTANT: blur is zero OUTSIDE the image
        //    (reference zero-pads the blur result before the sobel conv)
        for (int idx = tid; idx < BH * TW; idx += 256) {
            const int yy = idx / TW;
            const int xx = idx - yy * TW;
            float v = s_tmp[yy][xx]     * g0 + s_tmp[yy + 1][xx] * g1
                    + s_tmp[yy + 2][xx] * g2 + s_tmp[yy + 3][xx] * g3
                    + s_tmp[yy + 4][xx] * g4;
            const int gby = y0 - 1 + yy;
            const int gbx = x0 - 1 + xx;
            if ((unsigned)gby >= (unsigned)H || (unsigned)gbx >= (unsigned)W) v = 0.f;
            s_blur[yy][xx] = v;
        }
        __syncthreads();

        // 4. 3x3 sobel (cross-correlation, per lax.conv) with a sliding row window:
        //    thread owns 4 consecutive output rows -> 6 blur rows, 18 LDS reads not 36.
        {
            const int ybase = lyb * 4;  // blur row of output row ybase is ybase..ybase+2
            float a0 = s_blur[ybase][lx],     a1 = s_blur[ybase][lx + 1],     a2 = s_blur[ybase][lx + 2];
            float d0 = s_blur[ybase + 1][lx], d1 = s_blur[ybase + 1][lx + 1], d2 = s_blur[ybase + 1][lx + 2];
#pragma unroll
            for (int r = 0; r < 4; ++r) {
                const float c0 = s_blur[ybase + r + 2][lx];
                const float c1 = s_blur[ybase + r + 2][lx + 1];
                const float c2 = s_blur[ybase + r + 2][lx + 2];
                const float gx = sb[0] * a0 + sb[1] * a1 + sb[2] * a2
                               + sb[3] * d0 + sb[4] * d1 + sb[5] * d2
                               + sb[6] * c0 + sb[7] * c1 + sb[8] * c2;
                const float gy = sb[0] * a0 + sb[3] * a1 + sb[6] * a2
                               + sb[1] * d0 + sb[4] * d1 + sb[7] * d2
                               + sb[2] * c0 + sb[5] * c1 + sb[8] * c2;
                acc[r] += gx * gx + gy * gy;
                a0 = d0; a1 = d1; a2 = d2;
                d0 = c0; d1 = c1; d2 = c2;
            }
        }
        __syncthreads();  // protect LDS before next channel overwrites
    }

    // magnitude, store (unnormalized), track max
    float m = 0.f;
#pragma unroll
    for (int r = 0; r < 4; ++r) {
        const float v = sqrtf(acc[r]);
        const int yy = lyb * 4 + r;
        out[((size_t)b * H + (y0 + yy)) * W + (x0 + lx)] = v;
        m = fmaxf(m, v);
    }

    // block max: wave butterfly then cross-wave via LDS
#pragma unroll
    for (int off = 32; off > 0; off >>= 1)
        m = fmaxf(m, __shfl_xor(m, off, 64));
    if ((tid & 63) == 0) s_red[tid >> 6] = m;
    __syncthreads();
    if (tid == 0) {
        float bm = fmaxf(fmaxf(s_red[0], s_red[1]), fmaxf(s_red[2], s_red[3]));
        // values are non-negative: float bit pattern is monotone as unsigned
        atomicMax(gmax, __float_as_uint(bm));
    }
}

__global__ __launch_bounds__(256)
void normalize_kernel(float* __restrict__ out,
                      const unsigned int* __restrict__ gmax,
                      int n4) {
    const float maxv = __uint_as_float(*gmax);
    float4* o4 = (float4*)out;
    const int stride = gridDim.x * blockDim.x;
    for (int i = blockIdx.x * blockDim.x + threadIdx.x; i < n4; i += stride) {
        float4 v = o4[i];
        v.x = v.x / maxv;
        v.y = v.y / maxv;
        v.z = v.z / maxv;
        v.w = v.w / maxv;
        o4[i] = v;
    }
}

extern "C" void kernel_launch(void* const* d_in, const int* in_sizes, int n_in,
                              void* d_out, int out_size, void* d_ws, size_t ws_size,
                              hipStream_t stream) {
    const float* img   = (const float*)d_in[0];
    const float* gauss = (const float*)d_in[1];
    const float* sobel = (const float*)d_in[2];
    float* out = (float*)d_out;

    const int B = 32, H = 512, W = 512;
    unsigned int* gmax = (unsigned int*)d_ws;

    // zero the max accumulator (ws is re-poisoned to 0xAA before every launch)
    hipMemsetAsync(gmax, 0, sizeof(unsigned int), stream);

    const int tiles = (W / TX) * (H / TY) * B;  // 8 * 32 * 32 = 8192
    edge_fused_kernel<<<tiles, 256, 0, stream>>>(img, gauss, sobel, out, gmax, B, H, W);

    const int n4 = out_size / 4;  // 2097152 float4s
    normalize_kernel<<<2048, 256, 0, stream>>>(out, gmax, n4);
}

// Round 2
// 175.853 us; speedup vs baseline: 1.4593x; 1.4593x over previous
//
#include <hip/hip_runtime.h>
#include <math.h>

// Full-width strip design: each block computes a 512-wide x 16-row output strip
// for one batch image, looping the 3 channels and accumulating gx^2+gy^2.
// Vertical gaussian in registers (coalesced float2 global loads), horizontal
// gaussian register-staged through a single LDS buffer (in-place), sobel via
// u/v row-combo sliding window. No integer div/mod anywhere.
#define HH 512
#define WW 512
#define TH 16          // output rows per block
#define NROWS 18       // blur rows held (TH + 2 for sobel halo)
#define NLOAD 22       // img rows loaded (TH + 6: gauss halo 2 + sobel halo 1, each side)
#define VBW 520        // LDS row stride in floats (516 used + pad)

__global__ __launch_bounds__(256, 3)
void edge_fused_v2(const float* __restrict__ img,
                   const float* __restrict__ gauss,
                   float* __restrict__ out,
                   unsigned int* __restrict__ gmax) {
    __shared__ float vb[NROWS][VBW];   // 18*520*4 = 37,440 B -> 4 blocks/CU by LDS
    __shared__ float s_red[4];

    const int tid = threadIdx.x;
    const int bid = blockIdx.x;
    const int strip = bid & 31;        // 512/16 = 32 strips
    const int b     = bid >> 5;        // batch index
    const int ry0 = strip * TH;
    const int c0  = tid * 2;           // this thread owns columns c0, c0+1

    const float g0 = gauss[0], g1 = gauss[1], g2 = gauss[2], g3 = gauss[3], g4 = gauss[4];

    // One-time guard zeros: vb column slots for image cols -2,-1,512,513
    // (idx 0,1,514,515). Never overwritten (all phases write idx 2..513 only),
    // and they are correct for BOTH vb (img zero-pad) and blur (sobel zero-pad).
    if (tid < 72) {
        const int r = tid >> 2, k = tid & 3;
        vb[r][(k < 2) ? k : 512 + k] = 0.f;
    }

    // Rows ry0-3 .. ry0+18 all inside the image? (true for strips 1..30)
    const bool interior = (ry0 >= 3) && (ry0 + TH + 3 <= HH);

    float acc0[TH], acc1[TH];
#pragma unroll
    for (int o = 0; o < TH; ++o) { acc0[o] = 0.f; acc1[o] = 0.f; }

    for (int c = 0; c < 3; ++c) {
        const float* imgc = img + ((size_t)(b * 3 + c) * HH) * WW;

        // ---- phase 1: vertical gaussian -> LDS (cols c0, c0+1 as float2) ----
        float2 w[NLOAD];
        if (interior) {
#pragma unroll
            for (int i = 0; i < NLOAD; ++i)
                w[i] = *(const float2*)(imgc + (size_t)(ry0 - 3 + i) * WW + c0);
        } else {
#pragma unroll
            for (int i = 0; i < NLOAD; ++i) {
                const int y = ry0 - 3 + i;
                w[i] = (y >= 0 && y < HH)
                     ? *(const float2*)(imgc + (size_t)y * WW + c0)
                     : make_float2(0.f, 0.f);
            }
        }
#pragma unroll
        for (int r = 0; r < NROWS; ++r) {
            float2 s;
            s.x = g0*w[r].x + g1*w[r+1].x + g2*w[r+2].x + g3*w[r+3].x + g4*w[r+4].x;
            s.y = g0*w[r].y + g1*w[r+1].y + g2*w[r+2].y + g3*w[r+3].y + g4*w[r+4].y;
            *(float2*)&vb[r][c0 + 2] = s;   // idx c0+2 (even) -> 8B aligned
        }
        __syncthreads();

        // ---- phase 2a: horizontal gaussian into registers ----
        float2 bl[NROWS];
#pragma unroll
        for (int r = 0; r < NROWS; ++r) {
            const float2 A  = *(const float2*)&vb[r][c0];      // cols c0-2, c0-1
            const float2 Bv = *(const float2*)&vb[r][c0 + 2];  // cols c0,   c0+1
            const float2 C  = *(const float2*)&vb[r][c0 + 4];  // cols c0+2, c0+3
            bl[r].x = g0*A.x  + g1*A.y  + g2*Bv.x + g3*Bv.y + g4*C.x;
            bl[r].y = g0*A.y  + g1*Bv.x + g2*Bv.y + g3*C.x  + g4*C.y;
        }
        __syncthreads();

        // ---- phase 2b: write blur back in place (zero rows outside image:
        //      reference zero-pads blur before the sobel conv) ----
        if (interior) {
#pragma unroll
            for (int r = 0; r < NROWS; ++r)
                *(float2*)&vb[r][c0 + 2] = bl[r];
        } else {
#pragma unroll
            for (int r = 0; r < NROWS; ++r) {
                const int yb = ry0 - 1 + r;
                float2 v = bl[r];
                if (yb < 0 || yb >= HH) { v.x = 0.f; v.y = 0.f; }
                *(float2*)&vb[r][c0 + 2] = v;
            }
        }
        __syncthreads();

        // ---- phase 3: sobel (cross-correlation, per lax.conv) ----
        // per blur row & column: u = p[x-1]-p[x+1], v = p[x-1]+2p[x]+p[x+1]
        // gx(y) = u(y-1)+2u(y)+u(y+1) ; gy(y) = v(y-1)-v(y+1)
        float u0[2], v0[2], u1[2], v1[2];
#pragma unroll
        for (int r = 0; r < 2; ++r) {
            const float2 A  = *(const float2*)&vb[r][c0];
            const float2 Bv = *(const float2*)&vb[r][c0 + 2];
            const float2 C  = *(const float2*)&vb[r][c0 + 4];
            u0[r] = A.y - Bv.y;   v0[r] = A.y  + 2.f*Bv.x + Bv.y;
            u1[r] = Bv.x - C.x;   v1[r] = Bv.x + 2.f*Bv.y + C.x;
        }
#pragma unroll
        for (int o = 0; o < TH; ++o) {
            const int r = o + 2;
            const float2 A  = *(const float2*)&vb[r][c0];
            const float2 Bv = *(const float2*)&vb[r][c0 + 2];
            const float2 C  = *(const float2*)&vb[r][c0 + 4];
            const float nu0 = A.y - Bv.y,  nv0 = A.y  + 2.f*Bv.x + Bv.y;
            const float nu1 = Bv.x - C.x,  nv1 = Bv.x + 2.f*Bv.y + C.x;
            const float gx0 = u0[0] + 2.f*u0[1] + nu0;
            const float gy0 = v0[0] - nv0;
            const float gx1 = u1[0] + 2.f*u1[1] + nu1;
            const float gy1 = v1[0] - nv1;
            acc0[o] += gx0*gx0 + gy0*gy0;
            acc1[o] += gx1*gx1 + gy1*gy1;
            u0[0] = u0[1]; u0[1] = nu0;  v0[0] = v0[1]; v0[1] = nv0;
            u1[0] = u1[1]; u1[1] = nu1;  v1[0] = v1[1]; v1[1] = nv1;
        }
        __syncthreads();   // protect vb before next channel overwrites
    }

    // ---- epilogue: magnitude, store unnormalized, block max -> atomicMax ----
    float m = 0.f;
#pragma unroll
    for (int o = 0; o < TH; ++o) {
        float2 v;
        v.x = sqrtf(acc0[o]);
        v.y = sqrtf(acc1[o]);
        *(float2*)(out + ((size_t)b * HH + (ry0 + o)) * WW + c0) = v;
        m = fmaxf(m, fmaxf(v.x, v.y));
    }
#pragma unroll
    for (int off = 32; off > 0; off >>= 1)
        m = fmaxf(m, __shfl_xor(m, off, 64));
    if ((tid & 63) == 0) s_red[tid >> 6] = m;
    __syncthreads();
    if (tid == 0) {
        const float bm = fmaxf(fmaxf(s_red[0], s_red[1]), fmaxf(s_red[2], s_red[3]));
        // values non-negative: float bits are monotone as unsigned
        atomicMax(gmax, __float_as_uint(bm));
    }
}

__global__ __launch_bounds__(256)
void normalize_v2(float* __restrict__ out,
                  const unsigned int* __restrict__ gmax,
                  int n4) {
    const float inv = 1.0f / __uint_as_float(*gmax);  // one divide, then muls
    float4* o4 = (float4*)out;
    const int stride = gridDim.x * blockDim.x;
    for (int i = blockIdx.x * blockDim.x + threadIdx.x; i < n4; i += stride) {
        float4 v = o4[i];
        v.x *= inv; v.y *= inv; v.z *= inv; v.w *= inv;
        o4[i] = v;
    }
}

extern "C" void kernel_launch(void* const* d_in, const int* in_sizes, int n_in,
                              void* d_out, int out_size, void* d_ws, size_t ws_size,
                              hipStream_t stream) {
    const float* img   = (const float*)d_in[0];
    const float* gauss = (const float*)d_in[1];
    float* out = (float*)d_out;

    unsigned int* gmax = (unsigned int*)d_ws;
    hipMemsetAsync(gmax, 0, sizeof(unsigned int), stream);   // ws re-poisoned each launch

    const int B = 32;
    const int blocks = B * (HH / TH);   // 32 * 32 = 1024
    edge_fused_v2<<<blocks, 256, 0, stream>>>(img, gauss, out, gmax);

    const int n4 = out_size / 4;        // 2,097,152 float4s
    normalize_v2<<<4096, 256, 0, stream>>>(out, gmax, n4);
}